// Round 11
// baseline (325.230 us; speedup 1.0000x reference)
//
#include <hip/hip_runtime.h>
#include <math.h>

// Problem constants (from reference setup_inputs)
#define Bb 8
#define Cc 24
#define Hh 320
#define Ww 640
#define HWp (Hh * Ww)        // 204800
#define NPIX (Bb * HWp)      // 1638400
#define PIX_PER_THREAD 4
#define NXCD 8
#define BLOCKS_PER_XCD 200   // grid 1600 = 8 * 200
#define NT_START 12          // planes c<12 cached (L3-resident), c>=12 nt

// Native clang vector type: __builtin_nontemporal_load/store require a
// pointer to scalar-or-vector-of-scalar, not HIP's struct vector types.
typedef float f4 __attribute__((ext_vector_type(4)));

// v11 = v10 with L3-retention partitioning of the cost stream.
// Status: falsified levers = MLP (v4), occ/VGPR, gather (v6), run length
// (v7), logical volume (v6), XCD density (v10 clean null). Steady state:
// cost 157MB 100% cold-fetched, disp 157MB 100% L3-served (FETCH==cost),
// aggregate delivery 334MB/98us = 3.4 TB/s, fetch path 1.8 TB/s.
// Discriminating experiment: put planes c<12 of cost on the CACHED path.
// 78.6MB + disp 157MB = 236MB < 256MB L3 -> both should be retained across
// dispatches (same mechanism that retains disp today); planes c>=12 stay nt.
// Fetch drops to ~77MB, logical volume unchanged:
//   fetch-bound  -> dur ~55-75us (win, tune split next)
//   delivery-bound -> dur flat ~98us (establishes the 3.4 TB/s cap)
//   no retention -> FETCH stays 150MB (revert)
// Math identical to v8b/v10 (dv-carry, strict '>' ascending, nt stores).
__global__ __launch_bounds__(256, 8) void sparse_regression_kernel(
    const float* __restrict__ cost,
    const float* __restrict__ disp,
    float* __restrict__ pred,   // [B,H,W]   = NPIX floats
    float* __restrict__ prob)   // [B,2,H,W] = 2*NPIX floats
{
    // XCD-dense remap (kept from v10: proven perf-neutral, minimal diff).
    const int bid  = blockIdx.x;
    const int vbid = (bid & (NXCD - 1)) * BLOCKS_PER_XCD + (bid >> 3);

    const int t  = vbid * blockDim.x + threadIdx.x;
    const int p0 = t * PIX_PER_THREAD;
    if (p0 >= NPIX) return;   // never taken (grid exact) but pins the CFG/codegen

    const int b = p0 / HWp;
    const int q = p0 - b * HWp;      // h*W + w

    const size_t base = (size_t)b * Cc * HWp + q;
    const float* cbase = cost + base;
    const float* dbase = disp + base;

    float m1[PIX_PER_THREAD], m2[PIX_PER_THREAD];
    float dv1[PIX_PER_THREAD], dv2[PIX_PER_THREAD];
#pragma unroll
    for (int j = 0; j < PIX_PER_THREAD; ++j) {
        m1[j] = -INFINITY; m2[j] = -INFINITY;
        dv1[j] = 0.0f;     dv2[j] = 0.0f;
    }

    // Streaming top-2 over channels, carrying disparity values.
    // cost planes c<NT_START: cached (become L3-resident, never re-fetched);
    // cost planes c>=NT_START: non-temporal (streamed, no L3 alloc);
    // disp: cached (proven 100% L3-resident).
#pragma unroll
    for (int c = 0; c < Cc; ++c) {
        const f4* cp = (const f4*)(cbase + (size_t)c * HWp);
        const f4 cv = (c < NT_START) ? *cp : __builtin_nontemporal_load(cp);
        const f4 dv = *(const f4*)(dbase + (size_t)c * HWp);
#pragma unroll
        for (int j = 0; j < PIX_PER_THREAD; ++j) {
            const float val = cv[j];
            const float dvl = dv[j];
            const bool gt1 = val > m1[j];
            const bool gt2 = val > m2[j];
            m2[j]  = gt1 ? m1[j]  : (gt2 ? val : m2[j]);
            dv2[j] = gt1 ? dv1[j] : (gt2 ? dvl : dv2[j]);
            m1[j]  = gt1 ? val    : m1[j];
            dv1[j] = gt1 ? dvl    : dv1[j];
        }
    }

    f4 predo, p1o, p2o;
#pragma unroll
    for (int j = 0; j < PIX_PER_THREAD; ++j) {
        // softmax over {m1, m2}: p1 = 1/(1+exp(m2-m1)), m2-m1 <= 0
        const float e  = __expf(m2[j] - m1[j]);
        const float p1 = 1.0f / (1.0f + e);
        const float p2 = 1.0f - p1;
        predo[j] = dv1[j] * p1 + dv2[j] * p2;
        p1o[j] = p1;
        p2o[j] = p2;
    }

    // Coalesced non-temporal float4 stores (outputs never re-read).
    __builtin_nontemporal_store(predo, (f4*)(pred + p0));
    float* pb = prob + (size_t)b * 2 * HWp + q;
    __builtin_nontemporal_store(p1o, (f4*)(pb));
    __builtin_nontemporal_store(p2o, (f4*)(pb + HWp));
}

extern "C" void kernel_launch(void* const* d_in, const int* in_sizes, int n_in,
                              void* d_out, int out_size, void* d_ws, size_t ws_size,
                              hipStream_t stream) {
    const float* cost = (const float*)d_in[0];
    const float* disp = (const float*)d_in[1];
    float* pred = (float*)d_out;          // first NPIX floats
    float* prob = (float*)d_out + NPIX;   // next 2*NPIX floats

    const int threads = NPIX / PIX_PER_THREAD;   // 409600
    const int block = 256;
    const int grid = (threads + block - 1) / block;  // 1600 = 8*200, exact
    sparse_regression_kernel<<<grid, block, 0, stream>>>(cost, disp, pred, prob);
}

// Round 12
// 311.831 us; speedup vs baseline: 1.0430x; 1.0430x over previous
//
#include <hip/hip_runtime.h>
#include <math.h>

// Problem constants (from reference setup_inputs)
#define Bb 8
#define Cc 24
#define Hh 320
#define Ww 640
#define HWp (Hh * Ww)        // 204800
#define NPIX (Bb * HWp)      // 1638400
#define PIX_PER_THREAD 4
#define NXCD 8
#define BLOCKS_PER_XCD 200   // grid 1600 = 8 * 200

// Native clang vector type for __builtin_nontemporal_load/store.
typedef float f4 __attribute__((ext_vector_type(4)));

// v12 = v10 structure, index-carry scan (v1 math), all-nt cost stream.
// Ledger: falsified = MLP (v4), occ/VGPR, run length (v7), logical volume
// (v6), XCD density (v10), L3-retention partitioning (v11: reset() re-upload
// defeats it; mixed cached/nt drags to cached floor). Model: time =
// cost_fetch / fetch-rate (1.31 TB/s cached, 1.57 nt). Last untested
// structural variable in the NT regime: per-block stream count. v10 streams
// 48 interleaved 800KB-strided fronts (24 cost nt + 24 disp cached); this
// version streams only the 24 cost fronts and gathers the 2 selected disp
// values per pixel at the end (cached loads; disp is L3-resident, and
// v1===v6 proved the gather non-toxic at the cached floor).
// Outcomes: ~75-88us -> stream count was binding; flat ~98 -> fetch-path
// roofline confirmed, declare next round; 105+ -> revert to v10.
__global__ __launch_bounds__(256, 8) void sparse_regression_kernel(
    const float* __restrict__ cost,
    const float* __restrict__ disp,
    float* __restrict__ pred,   // [B,H,W]   = NPIX floats
    float* __restrict__ prob)   // [B,2,H,W] = 2*NPIX floats
{
    // XCD-dense remap (perf-neutral per v10; kept for minimal diff).
    const int bid  = blockIdx.x;
    const int vbid = (bid & (NXCD - 1)) * BLOCKS_PER_XCD + (bid >> 3);

    const int t  = vbid * blockDim.x + threadIdx.x;
    const int p0 = t * PIX_PER_THREAD;
    if (p0 >= NPIX) return;   // never taken (grid exact) but pins the CFG/codegen

    const int b = p0 / HWp;
    const int q = p0 - b * HWp;      // h*W + w

    const size_t base = (size_t)b * Cc * HWp + q;
    const float* cbase = cost + base;
    const float* dbase = disp + base;

    float m1[PIX_PER_THREAD], m2[PIX_PER_THREAD];
    int   idx1[PIX_PER_THREAD], idx2[PIX_PER_THREAD];
#pragma unroll
    for (int j = 0; j < PIX_PER_THREAD; ++j) {
        m1[j] = -INFINITY; m2[j] = -INFINITY;
        idx1[j] = 0;       idx2[j] = 0;
    }

    // Streaming top-2 over channels, cost only (24 nt fronts/block).
    // Strict '>' scanning c ascending reproduces lax.top_k's
    // lower-index-wins tie-breaking (v1-identical selects).
#pragma unroll
    for (int c = 0; c < Cc; ++c) {
        const f4 cv = __builtin_nontemporal_load(
            (const f4*)(cbase + (size_t)c * HWp));
#pragma unroll
        for (int j = 0; j < PIX_PER_THREAD; ++j) {
            const float val = cv[j];
            const bool gt1 = val > m1[j];
            const bool gt2 = val > m2[j];
            m2[j]   = gt1 ? m1[j]   : (gt2 ? val : m2[j]);
            idx2[j] = gt1 ? idx1[j] : (gt2 ? c   : idx2[j]);
            m1[j]   = gt1 ? val     : m1[j];
            idx1[j] = gt1 ? c       : idx1[j];
        }
    }

    // Gather the two selected disparity samples per pixel (cached loads;
    // disp is L3-resident per FETCH evidence; all 8 issued before any use).
    float d1[PIX_PER_THREAD], d2[PIX_PER_THREAD];
#pragma unroll
    for (int j = 0; j < PIX_PER_THREAD; ++j) {
        d1[j] = dbase[(size_t)idx1[j] * HWp + j];
        d2[j] = dbase[(size_t)idx2[j] * HWp + j];
    }

    f4 predo, p1o, p2o;
#pragma unroll
    for (int j = 0; j < PIX_PER_THREAD; ++j) {
        // softmax over {m1, m2}: p1 = 1/(1+exp(m2-m1)), m2-m1 <= 0
        const float e  = __expf(m2[j] - m1[j]);
        const float p1 = 1.0f / (1.0f + e);
        const float p2 = 1.0f - p1;
        predo[j] = d1[j] * p1 + d2[j] * p2;
        p1o[j] = p1;
        p2o[j] = p2;
    }

    // Coalesced non-temporal float4 stores (outputs never re-read).
    __builtin_nontemporal_store(predo, (f4*)(pred + p0));
    float* pb = prob + (size_t)b * 2 * HWp + q;
    __builtin_nontemporal_store(p1o, (f4*)(pb));
    __builtin_nontemporal_store(p2o, (f4*)(pb + HWp));
}

extern "C" void kernel_launch(void* const* d_in, const int* in_sizes, int n_in,
                              void* d_out, int out_size, void* d_ws, size_t ws_size,
                              hipStream_t stream) {
    const float* cost = (const float*)d_in[0];
    const float* disp = (const float*)d_in[1];
    float* pred = (float*)d_out;          // first NPIX floats
    float* prob = (float*)d_out + NPIX;   // next 2*NPIX floats

    const int threads = NPIX / PIX_PER_THREAD;   // 409600
    const int block = 256;
    const int grid = (threads + block - 1) / block;  // 1600 = 8*200, exact
    sparse_regression_kernel<<<grid, block, 0, stream>>>(cost, disp, pred, prob);
}